// Round 12
// baseline (478.488 us; speedup 1.0000x reference)
//
#include <hip/hip_runtime.h>
#include <hip/hip_bf16.h>
#include <math.h>

#define H 256
#define F 16
#define MUL 16
#define NB 8
#define LROW 296   // As row stride (elems): 148 dwords == 20 mod 32 -> 2-way (free)

typedef short bf16x8 __attribute__((ext_vector_type(8)));
typedef short bf16x4 __attribute__((ext_vector_type(4)));
typedef float f32x4 __attribute__((ext_vector_type(4)));
#define MFMA_B16(a, b, c) __builtin_amdgcn_mfma_f32_16x16x32_bf16(a, b, c, 0, 0, 0)

__device__ __forceinline__ float bf2f(__hip_bfloat16 x) { return __bfloat162float(x); }
__device__ __forceinline__ float silu(float x) { return x / (1.f + __expf(-x)); }
__device__ __forceinline__ short f2bs(float x)
{
    __hip_bfloat16 h = __float2bfloat16(x);
    short s; __builtin_memcpy(&s, &h, 2); return s;
}
__device__ __forceinline__ float bs2f(short s)
{
    __hip_bfloat16 h; __builtin_memcpy(&h, &s, 2); return __bfloat162float(h);
}

// ---------------- dtype sniffer: bf16 (flag=0) or fp32 (flag=1)?
__global__ __launch_bounds__(256) void k_sniff(const void* vec, int* flag)
{
    __shared__ int bad;
    int tid = threadIdx.x;
    if (tid == 0) bad = 0;
    __syncthreads();
    const __hip_bfloat16* hp = (const __hip_bfloat16*)vec;
    for (int i = tid; i < 1024; i += 256) {
        float f = bf2f(hp[i]);
        if (!(isfinite(f) && fabsf(f) <= 1.0f)) bad = 1;
    }
    __syncthreads();
    if (tid == 0) *flag = bad;
}

// ---------------- merged converter: 14 float inputs -> canonical fp32
struct ConvArgs {
    const void* src[14];
    float* dst[14];
    int cum[15];
};
__global__ __launch_bounds__(256) void k_conv_all(ConvArgs a, const int* __restrict__ flag)
{
    int gid = blockIdx.x * 256 + threadIdx.x;
    if (gid >= a.cum[14]) return;
    int k = 0;
    while (gid >= a.cum[k + 1]) k++;
    int i = gid - a.cum[k];
    float v = (*flag) ? ((const float*)a.src[k])[i]
                      : bf2f(((const __hip_bfloat16*)a.src[k])[i]);
    a.dst[k][i] = v;
}

// ---------------- merged weight swizzle: fp32 [K][N] -> bf16 frag-linear
struct SwzArgs {
    const float* src[9];
    __hip_bfloat16* dst[9];
    int K[9], Nc[9], cum[10];
};
__global__ __launch_bounds__(256) void k_swz_all(SwzArgs a)
{
    int gid = blockIdx.x * 256 + threadIdx.x;
    if (gid >= a.cum[9]) return;
    int j = 0;
    while (gid >= a.cum[j + 1]) j++;
    int idx = gid - a.cum[j];
    int kk = idx & 31;
    int n = (idx >> 5) % a.Nc[j];
    int kt = idx / (32 * a.Nc[j]);
    int k = kt * 32 + kk;
    float v = (k < a.K[j]) ? a.src[j][(size_t)k * a.Nc[j] + n] : 0.f;
    a.dst[j][idx] = __float2bfloat16(v);
}

// ---------------- W_out swizzle: [256][1] -> frag-linear [256x16], col 0 only
__global__ __launch_bounds__(256) void k_swz_wout(const float* __restrict__ Wout,
                                                  __hip_bfloat16* __restrict__ dst)
{
    int idx = blockIdx.x * 256 + threadIdx.x;   // 4096 total
    if (idx >= 8 * 16 * 32) return;
    int kk = idx & 31;
    int n = (idx >> 5) & 15;
    int kt = idx >> 9;
    float v = (n == 0) ? Wout[kt * 32 + kk] : 0.f;
    dst[idx] = __float2bfloat16(v);
}

// ---------------- CSR build
__global__ __launch_bounds__(256) void k_hist(const int* __restrict__ snd,
                                              int* __restrict__ cnt, int E)
{
    int e = blockIdx.x * 256 + threadIdx.x;
    if (e < E) atomicAdd(&cnt[snd[e]], 1);
}

__global__ __launch_bounds__(256) void k_scan(const int* __restrict__ cnt,
                                              int* __restrict__ off,
                                              int* __restrict__ cur, int N)
{
    __shared__ int sums[256];
    int tid = threadIdx.x;
    int chunk = (N + 255) / 256;
    int base = tid * chunk;
    int s = 0;
    for (int i = 0; i < chunk; i++) { int idx = base + i; if (idx < N) s += cnt[idx]; }
    sums[tid] = s;
    __syncthreads();
    for (int d = 1; d < 256; d <<= 1) {
        int v = (tid >= d) ? sums[tid - d] : 0;
        __syncthreads();
        sums[tid] += v;
        __syncthreads();
    }
    int run = (tid == 0) ? 0 : sums[tid - 1];
    for (int i = 0; i < chunk; i++) {
        int idx = base + i;
        if (idx < N) { off[idx] = run; cur[idx] = run; run += cnt[idx]; }
    }
    if (tid == 255) off[N] = run;
}

__global__ __launch_bounds__(256) void k_cscatter(const int* __restrict__ snd,
                                                  int* __restrict__ cur,
                                                  int* __restrict__ eidx, int E)
{
    int e = blockIdx.x * 256 + threadIdx.x;
    if (e >= E) return;
    int p = atomicAdd(&cur[snd[e]], 1);
    eidx[p] = e;
}

// ---------------- geometry: u, Y(16) fp32; fbuf[E][64] bf16 = [bessel8|na_s|na_r|0]
__global__ __launch_bounds__(256) void k_geom(
    const float* __restrict__ vec, const float* __restrict__ na,
    const int* __restrict__ snd, const int* __restrict__ rcv,
    float* __restrict__ ubuf, float* __restrict__ Ybuf,
    __hip_bfloat16* __restrict__ fbuf, int E)
{
    int e = blockIdx.x * blockDim.x + threadIdx.x;
    if (e >= E) return;
    float vx = vec[3 * e + 0], vy = vec[3 * e + 1], vz = vec[3 * e + 2];
    float d = sqrtf(vx * vx + vy * vy + vz * vz);

    float d3 = d * d * d;
    float d6 = d3 * d3, d7 = d6 * d, d8 = d7 * d;
    float u = 1.f - 28.f * d6 + 48.f * d7 - 21.f * d8;
    u = (d < 1.f) ? u : 0.f;
    ubuf[e] = u;

    float invd = 1.f / d;
    const float SQ2 = 1.41421356237309515f;
    const float PI = 3.14159265358979323846f;
    __hip_bfloat16* fp = fbuf + (size_t)e * 64;
#pragma unroll
    for (int k = 1; k <= NB; k++)
        fp[k - 1] = __float2bfloat16(SQ2 * sinf((float)k * PI * d) * invd);
    int s = snd[e], r = rcv[e];
#pragma unroll
    for (int j = 0; j < 16; j++) fp[8 + j] = __float2bfloat16(na[(size_t)s * F + j]);
#pragma unroll
    for (int j = 0; j < 16; j++) fp[24 + j] = __float2bfloat16(na[(size_t)r * F + j]);
#pragma unroll
    for (int j = 40; j < 64; j++) fp[j] = __float2bfloat16(0.f);

    float x = vx * invd, y = vy * invd, z = vz * invd;
    const float s3 = 1.7320508075688772f;
    const float s5 = 2.2360679774997896f;
    const float s15 = 3.8729833462074170f;
    const float s7 = 2.6457513110645907f;
    const float c33 = 2.0916500663351889f;
    const float c32 = 10.246950765959598f;
    const float c31 = 1.6201851746019651f;
    float* Yp = Ybuf + (size_t)e * 16;
    Yp[0] = 1.f;
    Yp[1] = s3 * x;  Yp[2] = s3 * y;  Yp[3] = s3 * z;
    Yp[4] = s15 * x * y;  Yp[5] = s15 * y * z;
    Yp[6] = 0.5f * s5 * (3.f * z * z - 1.f);
    Yp[7] = s15 * x * z;
    Yp[8] = 0.5f * s15 * (x * x - y * y);
    Yp[9] = c33 * y * (3.f * x * x - y * y);
    Yp[10] = c32 * x * y * z;
    Yp[11] = c31 * y * (5.f * z * z - 1.f);
    Yp[12] = 0.5f * s7 * (5.f * z * z * z - 3.f * z);
    Yp[13] = c31 * x * (5.f * z * z - 1.f);
    Yp[14] = 0.5f * c32 * z * (x * x - y * y);
    Yp[15] = c33 * x * (x * x - 3.f * y * y);
}

// =====================================================================
// Tile kernels (operand-swapped, SINGLE 37.9 KB LDS buffer -> 4 blocks/CU):
// A-operand = weight frag, B-operand = x frag; acc: edge=lane&15,
// outcol=quad*4+reg. y-tile overwrites the x-tile after GEMM1; residual
// x_old is re-read from global xb (streaming, +64MB but 2x occupancy).
// Block = 64 edges x 4 waves; wave w owns outcol slice 64w..64w+63.
// =====================================================================

// ---------------- MFMA embed tile kernel
__global__ __launch_bounds__(256) void k_embed_mfma(
    const __hip_bfloat16* __restrict__ fbuf,
    const __hip_bfloat16* __restrict__ We0s, const float* __restrict__ be0,
    const __hip_bfloat16* __restrict__ We1s, const float* __restrict__ be1,
    const __hip_bfloat16* __restrict__ Wv0s, const __hip_bfloat16* __restrict__ Wlws0,
    const float* __restrict__ ubuf,
    __hip_bfloat16* __restrict__ xb, float* __restrict__ abuf,
    float* __restrict__ wbuf)
{
    __shared__ __align__(16) __hip_bfloat16 As[64 * LROW];  // 37888 B
    int tid = threadIdx.x;
    int w = tid >> 6, l = tid & 63;
    int lm = l & 15, lq = l >> 4;
    int eb = blockIdx.x * 64;

    // stage fbuf tile [64x64] -> As cols 0..64
#pragma unroll
    for (int i = 0; i < 2; i++) {
        int c = tid + 256 * i;
        int row = c >> 3, kc = c & 7;
        *(bf16x8*)(As + row * LROW + kc * 8) =
            *(const bf16x8*)(fbuf + (size_t)(eb + row) * 64 + kc * 8);
    }
    __syncthreads();

    // GEMM1: [64x64] @ [64x256]  (A=W frag, B=x frag)
    f32x4 acc[4][4];
#pragma unroll
    for (int mt = 0; mt < 4; mt++)
#pragma unroll
        for (int nt = 0; nt < 4; nt++) acc[mt][nt] = (f32x4){0.f, 0.f, 0.f, 0.f};
#pragma unroll
    for (int kt = 0; kt < 2; kt++) {
        bf16x8 aw[4];
#pragma unroll
        for (int nt = 0; nt < 4; nt++)
            aw[nt] = *(const bf16x8*)(We0s + ((size_t)(kt * 256 + w * 64 + nt * 16 + lm) * 32 + lq * 8));
#pragma unroll
        for (int mt = 0; mt < 4; mt++) {
            bf16x8 bx = *(const bf16x8*)(As + (mt * 16 + lm) * LROW + kt * 32 + lq * 8);
#pragma unroll
            for (int nt = 0; nt < 4; nt++) acc[mt][nt] = MFMA_B16(aw[nt], bx, acc[mt][nt]);
        }
    }
    __syncthreads();   // all GEMM1 reads done before y0 overwrites As
    // y0 = silu(acc + b0) -> As cols 0..256, packed b64
#pragma unroll
    for (int nt = 0; nt < 4; nt++) {
        int cb = w * 64 + nt * 16 + lq * 4;
        f32x4 bb = *(const f32x4*)(be0 + cb);
#pragma unroll
        for (int mt = 0; mt < 4; mt++) {
            int row = mt * 16 + lm;
            bf16x4 v = {f2bs(silu(acc[mt][nt][0] + bb[0])), f2bs(silu(acc[mt][nt][1] + bb[1])),
                        f2bs(silu(acc[mt][nt][2] + bb[2])), f2bs(silu(acc[mt][nt][3] + bb[3]))};
            *(bf16x4*)(As + row * LROW + cb) = v;
        }
    }
    __syncthreads();

    // GEMM2: [64x256] @ [256x256]
#pragma unroll
    for (int mt = 0; mt < 4; mt++)
#pragma unroll
        for (int nt = 0; nt < 4; nt++) acc[mt][nt] = (f32x4){0.f, 0.f, 0.f, 0.f};
#pragma unroll
    for (int kt = 0; kt < 8; kt++) {
        bf16x8 aw[4];
#pragma unroll
        for (int nt = 0; nt < 4; nt++)
            aw[nt] = *(const bf16x8*)(We1s + ((size_t)(kt * 256 + w * 64 + nt * 16 + lm) * 32 + lq * 8));
#pragma unroll
        for (int mt = 0; mt < 4; mt++) {
            bf16x8 bx = *(const bf16x8*)(As + (mt * 16 + lm) * LROW + kt * 32 + lq * 8);
#pragma unroll
            for (int nt = 0; nt < 4; nt++) acc[mt][nt] = MFMA_B16(aw[nt], bx, acc[mt][nt]);
        }
    }
    __syncthreads();   // all GEMM2 reads done before x1 overwrites As
    // epilogue: x1 = silu(.)*u -> xb global (8B stores) and As (b64)
#pragma unroll
    for (int nt = 0; nt < 4; nt++) {
        int cb = w * 64 + nt * 16 + lq * 4;
        f32x4 bb = *(const f32x4*)(be1 + cb);
#pragma unroll
        for (int mt = 0; mt < 4; mt++) {
            int row = mt * 16 + lm;
            float uu = ubuf[eb + row];
            bf16x4 v = {f2bs(silu(acc[mt][nt][0] + bb[0]) * uu),
                        f2bs(silu(acc[mt][nt][1] + bb[1]) * uu),
                        f2bs(silu(acc[mt][nt][2] + bb[2]) * uu),
                        f2bs(silu(acc[mt][nt][3] + bb[3]) * uu)};
            *(bf16x4*)(As + row * LROW + cb) = v;
            *(bf16x4*)(xb + (size_t)(eb + row) * H + cb) = v;
        }
    }
    __syncthreads();

    // GEMM3: a = x@Wv0, w = x@Wlw0 -- wave w owns edges w*16..w*16+15
    f32x4 av = (f32x4){0.f, 0.f, 0.f, 0.f};
    f32x4 aw2 = (f32x4){0.f, 0.f, 0.f, 0.f};
#pragma unroll
    for (int kt = 0; kt < 8; kt++) {
        bf16x8 bx = *(const bf16x8*)(As + (w * 16 + lm) * LROW + kt * 32 + lq * 8);
        bf16x8 a_v = *(const bf16x8*)(Wv0s + ((size_t)(kt * 16 + lm) * 32 + lq * 8));
        bf16x8 a_w = *(const bf16x8*)(Wlws0 + ((size_t)(kt * 16 + lm) * 32 + lq * 8));
        av = MFMA_B16(a_v, bx, av);
        aw2 = MFMA_B16(a_w, bx, aw2);
    }
    *(f32x4*)(abuf + (size_t)(eb + w * 16 + lm) * 16 + lq * 4) = av;
    *(f32x4*)(wbuf + (size_t)(eb + w * 16 + lm) * 16 + lq * 4) = aw2;
}

// ---------------- CSR gather: wYn[n,m,i] = inv * sum_e w[e,m]*Y[e,i]
__global__ __launch_bounds__(256) void k_gather(
    const int* __restrict__ off, const int* __restrict__ eidx,
    const float* __restrict__ wbuf, const float* __restrict__ Ybuf,
    float* __restrict__ wYn)
{
    __shared__ float ws[16][16];
    __shared__ float Ysh[16][16];
    int n = blockIdx.x;
    int tid = threadIdx.x;
    int m = tid >> 4, i = tid & 15;
    int beg = off[n], end = off[n + 1];
    float acc = 0.f;
    for (int c = beg; c < end; c += 16) {
        int ne = min(16, end - c);
        int j = tid >> 4, k = tid & 15;
        if (j < ne) {
            int e = eidx[c + j];
            ws[j][k] = wbuf[(size_t)e * 16 + k];
            Ysh[j][k] = Ybuf[(size_t)e * 16 + k];
        }
        __syncthreads();
        for (int j2 = 0; j2 < ne; j2++) acc += ws[j2][m] * Ysh[j2][i];
        __syncthreads();
    }
    wYn[(size_t)n * 256 + m * 16 + i] = acc * 0.25f;
}

// ---------------- MFMA layer tile kernel (operand-swapped, single buffer)
__global__ __launch_bounds__(256) void k_layer_mfma(
    __hip_bfloat16* __restrict__ xb, const float* __restrict__ abuf,
    const float* __restrict__ Ybuf, const float* __restrict__ ubuf,
    const int* __restrict__ snd, const int* __restrict__ rcv,
    const float* __restrict__ wYn0, const float* __restrict__ wYn1,
    const float* __restrict__ Wlsh,
    const __hip_bfloat16* __restrict__ W1s, const float* __restrict__ b1,
    const __hip_bfloat16* __restrict__ W2s, const float* __restrict__ b2,
    const __hip_bfloat16* __restrict__ Wlwn, float* __restrict__ wbufn,
    const __hip_bfloat16* __restrict__ Wouts, float* __restrict__ nacc,
    int layer)
{
    __shared__ __align__(16) __hip_bfloat16 As[64 * LROW];  // 37888 B
    int tid = threadIdx.x;
    int w = tid >> 6, l = tid & 63;
    int lm = l & 15, lq = l >> 4;
    int eb = blockIdx.x * 64;

    // stage x tile [64x256] -> As cols 0..256
#pragma unroll
    for (int i = 0; i < 8; i++) {
        int c = tid + 256 * i;
        int row = c >> 5, kc = c & 31;
        *(bf16x8*)(As + row * LROW + kc * 8) =
            *(const bf16x8*)(xb + (size_t)(eb + row) * H + kc * 8);
    }
    // vv prologue -> As cols 256..272; zeros 272..288
    {
        int el = tid & 63;
        int mh = (tid >> 6) * 4;
        int ge = eb + el;
        int s = snd[ge];
        const float* w0 = wYn0 + (size_t)s * 256;
        float Yr[16];
        if (layer == 1) {
#pragma unroll
            for (int i = 0; i < 16; i++)
                Yr[i] = Ybuf[(size_t)ge * 16 + i] * Wlsh[i * 16];
        }
#pragma unroll
        for (int mi = 0; mi < 4; mi++) {
            int m = mh + mi;
            float a = abuf[(size_t)ge * 16 + m];
            float vv;
            if (layer == 0) {
                vv = w0[m * 16] * a;  // Y[e][0] == 1
            } else {
                float t = 0.f;
#pragma unroll
                for (int i = 0; i < 16; i++) t += w0[m * 16 + i] * Yr[i];
                vv = wYn1[(size_t)s * 256 + m * 16] * a * t;
            }
            As[el * LROW + 256 + m] = __float2bfloat16(vv);
        }
        if (tid < 64) {
#pragma unroll
            for (int j = 0; j < 16; j++) As[tid * LROW + 272 + j] = __float2bfloat16(0.f);
        }
    }
    __syncthreads();

    // GEMM1: [64x288] @ [288x256]
    f32x4 acc[4][4];
#pragma unroll
    for (int mt = 0; mt < 4; mt++)
#pragma unroll
        for (int nt = 0; nt < 4; nt++) acc[mt][nt] = (f32x4){0.f, 0.f, 0.f, 0.f};
#pragma unroll
    for (int kt = 0; kt < 9; kt++) {
        bf16x8 aw[4];
#pragma unroll
        for (int nt = 0; nt < 4; nt++)
            aw[nt] = *(const bf16x8*)(W1s + ((size_t)(kt * 256 + w * 64 + nt * 16 + lm) * 32 + lq * 8));
#pragma unroll
        for (int mt = 0; mt < 4; mt++) {
            bf16x8 bx = *(const bf16x8*)(As + (mt * 16 + lm) * LROW + kt * 32 + lq * 8);
#pragma unroll
            for (int nt = 0; nt < 4; nt++) acc[mt][nt] = MFMA_B16(aw[nt], bx, acc[mt][nt]);
        }
    }
    __syncthreads();   // all GEMM1 reads done before y1 overwrites As
    // y1 = silu(acc + b1) -> As cols 0..256 packed
#pragma unroll
    for (int nt = 0; nt < 4; nt++) {
        int cb = w * 64 + nt * 16 + lq * 4;
        f32x4 bb = *(const f32x4*)(b1 + cb);
#pragma unroll
        for (int mt = 0; mt < 4; mt++) {
            int row = mt * 16 + lm;
            bf16x4 v = {f2bs(silu(acc[mt][nt][0] + bb[0])), f2bs(silu(acc[mt][nt][1] + bb[1])),
                        f2bs(silu(acc[mt][nt][2] + bb[2])), f2bs(silu(acc[mt][nt][3] + bb[3]))};
            *(bf16x4*)(As + row * LROW + cb) = v;
        }
    }
    __syncthreads();

    // GEMM2: [64x256] @ [256x256]
#pragma unroll
    for (int mt = 0; mt < 4; mt++)
#pragma unroll
        for (int nt = 0; nt < 4; nt++) acc[mt][nt] = (f32x4){0.f, 0.f, 0.f, 0.f};
#pragma unroll
    for (int kt = 0; kt < 8; kt++) {
        bf16x8 aw[4];
#pragma unroll
        for (int nt = 0; nt < 4; nt++)
            aw[nt] = *(const bf16x8*)(W2s + ((size_t)(kt * 256 + w * 64 + nt * 16 + lm) * 32 + lq * 8));
#pragma unroll
        for (int mt = 0; mt < 4; mt++) {
            bf16x8 bx = *(const bf16x8*)(As + (mt * 16 + lm) * LROW + kt * 32 + lq * 8);
#pragma unroll
            for (int nt = 0; nt < 4; nt++) acc[mt][nt] = MFMA_B16(aw[nt], bx, acc[mt][nt]);
        }
    }
    __syncthreads();   // all GEMM2 reads done before x_new overwrites As
    // epilogue: xnew = (x_old + u*silu(acc+b2))/sqrt2; x_old re-read from
    // global xb (xb not yet modified this dispatch for these cells).
    const float rs2 = 0.70710678118654752f;
#pragma unroll
    for (int nt = 0; nt < 4; nt++) {
        int cb = w * 64 + nt * 16 + lq * 4;
        f32x4 bb = *(const f32x4*)(b2 + cb);
#pragma unroll
        for (int mt = 0; mt < 4; mt++) {
            int row = mt * 16 + lm;
            float uu = ubuf[eb + row];
            bf16x4 xo = *(const bf16x4*)(xb + (size_t)(eb + row) * H + cb);
            bf16x4 v;
#pragma unroll
            for (int r = 0; r < 4; r++) {
                float xn = (bs2f(xo[r]) + uu * silu(acc[mt][nt][r] + bb[r])) * rs2;
                v[r] = f2bs(xn);
            }
            *(bf16x4*)(As + row * LROW + cb) = v;
            if (layer == 0) *(bf16x4*)(xb + (size_t)(eb + row) * H + cb) = v;
        }
    }
    __syncthreads();

    if (layer == 0) {
        // wcomp: w = x_new @ Wlwn -- wave w owns edges w*16..w*16+15
        f32x4 cw = (f32x4){0.f, 0.f, 0.f, 0.f};
#pragma unroll
        for (int kt = 0; kt < 8; kt++) {
            bf16x8 bx = *(const bf16x8*)(As + (w * 16 + lm) * LROW + kt * 32 + lq * 8);
            bf16x8 a = *(const bf16x8*)(Wlwn + ((size_t)(kt * 16 + lm) * 32 + lq * 8));
            cw = MFMA_B16(a, bx, cw);
        }
        *(f32x4*)(wbufn + (size_t)(eb + w * 16 + lm) * 16 + lq * 4) = cw;
    } else {
        // out-proj: edge_out = (x_new @ W_out) * u -> atomicAdd nacc[rcv]
        f32x4 co = (f32x4){0.f, 0.f, 0.f, 0.f};
#pragma unroll
        for (int kt = 0; kt < 8; kt++) {
            bf16x8 bx = *(const bf16x8*)(As + (w * 16 + lm) * LROW + kt * 32 + lq * 8);
            bf16x8 a = *(const bf16x8*)(Wouts + ((size_t)(kt * 16 + lm) * 32 + lq * 8));
            co = MFMA_B16(a, bx, co);
        }
        if (lq == 0) {
            int e = eb + w * 16 + lm;
            atomicAdd(&nacc[rcv[e]], co[0] * ubuf[e]);
        }
    }
}

__global__ __launch_bounds__(256) void k_final(
    const float* __restrict__ nacc, void* __restrict__ out, const int* __restrict__ flag,
    float inv, int N)
{
    int n = blockIdx.x * 256 + threadIdx.x;
    if (n >= N) return;
    float v = nacc[n] * inv;
    if (*flag) ((float*)out)[n] = v;
    else       ((__hip_bfloat16*)out)[n] = __float2bfloat16(v);
}

extern "C" void kernel_launch(void* const* d_in, const int* in_sizes, int n_in,
                              void* d_out, int out_size, void* d_ws, size_t ws_size,
                              hipStream_t stream)
{
    const int E = in_sizes[2];      // 131072
    const int N = in_sizes[0] / F;  // 8192
    (void)n_in; (void)ws_size; (void)out_size;

    char* wsb = (char*)d_ws;
    size_t off = 0;
    int* flag = (int*)wsb; off += 256;

    const int fidx[14] = {0, 1, 4, 5, 6, 7, 8, 9, 10, 11, 12, 13, 14, 15};
    float* canon[14];
    for (int k = 0; k < 14; k++) {
        canon[k] = (float*)(wsb + off);
        off += (size_t)in_sizes[fidx[k]] * 4;
        off = (off + 255) & ~(size_t)255;
    }
    const float* naC   = canon[0];
    const float* vecC  = canon[1];
    const float* We0C  = canon[2];
    const float* be0C  = canon[3];
    const float* We1C  = canon[4];
    const float* be1C  = canon[5];
    const float* Wv0C  = canon[6];
    const float* WlwC  = canon[7];
    const float* WlshC = canon[8];
    const float* Wly1C = canon[9];
    const float* bly1C = canon[10];
    const float* Wly2C = canon[11];
    const float* bly2C = canon[12];
    const float* WoutC = canon[13];

    // swizzled bf16 weights
    __hip_bfloat16* We0s  = (__hip_bfloat16*)(wsb + off); off += 64 * 256 * 2;
    __hip_bfloat16* We1s  = (__hip_bfloat16*)(wsb + off); off += 256 * 256 * 2;
    __hip_bfloat16* Wv0s  = (__hip_bfloat16*)(wsb + off); off += 256 * 16 * 2;
    __hip_bfloat16* Wlws0 = (__hip_bfloat16*)(wsb + off); off += 256 * 16 * 2;
    __hip_bfloat16* Wlws1 = (__hip_bfloat16*)(wsb + off); off += 256 * 16 * 2;
    __hip_bfloat16* W1s0  = (__hip_bfloat16*)(wsb + off); off += 288 * 256 * 2;
    __hip_bfloat16* W1s1  = (__hip_bfloat16*)(wsb + off); off += 288 * 256 * 2;
    __hip_bfloat16* W2s0  = (__hip_bfloat16*)(wsb + off); off += 256 * 256 * 2;
    __hip_bfloat16* W2s1  = (__hip_bfloat16*)(wsb + off); off += 256 * 256 * 2;
    __hip_bfloat16* Wouts = (__hip_bfloat16*)(wsb + off); off += 256 * 16 * 2;
    off = (off + 255) & ~(size_t)255;

    __hip_bfloat16* xbuf = (__hip_bfloat16*)(wsb + off); off += (size_t)E * H * 2;
    // fbuf (16 MB) dies after k_embed; wYn0/wYn1 (8+8 MB) alias the same region
    __hip_bfloat16* fbuf = (__hip_bfloat16*)(wsb + off);
    float* wYn0 = (float*)(wsb + off);
    float* wYn1 = (float*)(wsb + off + (size_t)N * H * 4);
    off += (size_t)E * 64 * 2;
    float* ubuf = (float*)(wsb + off); off += (size_t)E * 4;
    float* Ybuf = (float*)(wsb + off); off += (size_t)E * 16 * 4;
    float* abuf = (float*)(wsb + off); off += (size_t)E * 16 * 4;
    float* wbuf = (float*)(wsb + off); off += (size_t)E * 16 * 4;
    float* nacc = (float*)(wsb + off); off += (size_t)N * 4;
    int* cnt  = (int*)(wsb + off); off += (size_t)N * 4;
    int* offb = (int*)(wsb + off); off += (size_t)(N + 1) * 4;
    int* cur  = (int*)(wsb + off); off += (size_t)N * 4;
    int* eidx = (int*)(wsb + off); off += (size_t)E * 4;

    const int* snd = (const int*)d_in[2];
    const int* rcv = (const int*)d_in[3];
    const float inv = 0.25f;
    const int nb64 = E / 64;

    // dtype sniff + merged canonicalization
    k_sniff<<<1, 256, 0, stream>>>(d_in[1], flag);
    {
        ConvArgs ca;
        int c = 0;
        for (int k = 0; k < 14; k++) {
            ca.src[k] = d_in[fidx[k]];
            ca.dst[k] = canon[k];
            ca.cum[k] = c;
            c += in_sizes[fidx[k]];
        }
        ca.cum[14] = c;
        k_conv_all<<<(c + 255) / 256, 256, 0, stream>>>(ca, flag);
    }

    // merged weight swizzles
    {
        SwzArgs sa;
        const float* srcs[9] = {We0C, We1C, Wv0C, WlwC, WlwC + 256 * 16,
                                Wly1C, Wly1C + 272 * 256, Wly2C, Wly2C + 256 * 256};
        __hip_bfloat16* dsts[9] = {We0s, We1s, Wv0s, Wlws0, Wlws1, W1s0, W1s1, W2s0, W2s1};
        int Ks[9]    = {40, 256, 256, 256, 256, 272, 272, 256, 256};
        int Ncs[9]   = {256, 256, 16, 16, 16, 256, 256, 256, 256};
        int Kpads[9] = {64, 256, 256, 256, 256, 288, 288, 256, 256};
        int c = 0;
        for (int j = 0; j < 9; j++) {
            sa.src[j] = srcs[j]; sa.dst[j] = dsts[j];
            sa.K[j] = Ks[j]; sa.Nc[j] = Ncs[j];
            sa.cum[j] = c;
            c += (Kpads[j] >> 5) * Ncs[j] * 32;
        }
        sa.cum[9] = c;
        k_swz_all<<<(c + 255) / 256, 256, 0, stream>>>(sa);
    }
    k_swz_wout<<<16, 256, 0, stream>>>(WoutC, Wouts);

    // sender CSR
    hipMemsetAsync(cnt, 0, (size_t)N * sizeof(int), stream);
    k_hist<<<(E + 255) / 256, 256, 0, stream>>>(snd, cnt, E);
    k_scan<<<1, 256, 0, stream>>>(cnt, offb, cur, N);
    k_cscatter<<<(E + 255) / 256, 256, 0, stream>>>(snd, cur, eidx, E);

    k_geom<<<(E + 255) / 256, 256, 0, stream>>>(vecC, naC, snd, rcv, ubuf, Ybuf, fbuf, E);
    k_embed_mfma<<<nb64, 256, 0, stream>>>(fbuf, We0s, be0C, We1s, be1C, Wv0s, Wlws0,
                                           ubuf, xbuf, abuf, wbuf);

    // layer 0 (emits w for layer 1 into wbuf)
    k_gather<<<N, 256, 0, stream>>>(offb, eidx, wbuf, Ybuf, wYn0);
    k_layer_mfma<<<nb64, 256, 0, stream>>>(xbuf, abuf, Ybuf, ubuf, snd, rcv, wYn0, wYn0,
                                           WlshC, W1s0, bly1C, W2s0, bly2C,
                                           Wlws1, wbuf, (const __hip_bfloat16*)nullptr,
                                           (float*)nullptr, 0);
    // layer 1 (residual in LDS; fused output projection -> nacc)
    hipMemsetAsync(nacc, 0, (size_t)N * sizeof(float), stream);
    k_gather<<<N, 256, 0, stream>>>(offb, eidx, wbuf, Ybuf, wYn1);
    k_layer_mfma<<<nb64, 256, 0, stream>>>(xbuf, abuf, Ybuf, ubuf, snd, rcv, wYn0, wYn1,
                                           WlshC, W1s1, bly1C + H, W2s1, bly2C + H,
                                           (const __hip_bfloat16*)nullptr, (float*)nullptr,
                                           Wouts, nacc, 1);

    k_final<<<(N + 255) / 256, 256, 0, stream>>>(nacc, d_out, flag, inv, N);
}

// Round 13
// 434.141 us; speedup vs baseline: 1.1022x; 1.1022x over previous
//
#include <hip/hip_runtime.h>
#include <hip/hip_bf16.h>
#include <math.h>

#define H 256
#define F 16
#define MUL 16
#define NB 8
#define LROW 296   // As row stride (elems): 148 dwords == 20 mod 32 -> 2-way (free)
#define YROW 264   // Ys row stride (elems): 132 dwords == 4 mod 32  -> 2-way (free)

typedef short bf16x8 __attribute__((ext_vector_type(8)));
typedef short bf16x4 __attribute__((ext_vector_type(4)));
typedef float f32x4 __attribute__((ext_vector_type(4)));
#define MFMA_B16(a, b, c) __builtin_amdgcn_mfma_f32_16x16x32_bf16(a, b, c, 0, 0, 0)

__device__ __forceinline__ float bf2f(__hip_bfloat16 x) { return __bfloat162float(x); }
__device__ __forceinline__ float silu(float x) { return x / (1.f + __expf(-x)); }
__device__ __forceinline__ short f2bs(float x)
{
    __hip_bfloat16 h = __float2bfloat16(x);
    short s; __builtin_memcpy(&s, &h, 2); return s;
}
__device__ __forceinline__ float bs2f(short s)
{
    __hip_bfloat16 h; __builtin_memcpy(&h, &s, 2); return __bfloat162float(h);
}

// ---------------- dtype sniffer: bf16 (flag=0) or fp32 (flag=1)?
__global__ __launch_bounds__(256) void k_sniff(const void* vec, int* flag)
{
    __shared__ int bad;
    int tid = threadIdx.x;
    if (tid == 0) bad = 0;
    __syncthreads();
    const __hip_bfloat16* hp = (const __hip_bfloat16*)vec;
    for (int i = tid; i < 1024; i += 256) {
        float f = bf2f(hp[i]);
        if (!(isfinite(f) && fabsf(f) <= 1.0f)) bad = 1;
    }
    __syncthreads();
    if (tid == 0) *flag = bad;
}

// ---------------- merged converter: 14 float inputs -> canonical fp32
struct ConvArgs {
    const void* src[14];
    float* dst[14];
    int cum[15];
};
__global__ __launch_bounds__(256) void k_conv_all(ConvArgs a, const int* __restrict__ flag)
{
    int gid = blockIdx.x * 256 + threadIdx.x;
    if (gid >= a.cum[14]) return;
    int k = 0;
    while (gid >= a.cum[k + 1]) k++;
    int i = gid - a.cum[k];
    float v = (*flag) ? ((const float*)a.src[k])[i]
                      : bf2f(((const __hip_bfloat16*)a.src[k])[i]);
    a.dst[k][i] = v;
}

// ---------------- merged weight swizzle: fp32 [K][N] -> bf16 frag-linear
struct SwzArgs {
    const float* src[9];
    __hip_bfloat16* dst[9];
    int K[9], Nc[9], cum[10];
};
__global__ __launch_bounds__(256) void k_swz_all(SwzArgs a)
{
    int gid = blockIdx.x * 256 + threadIdx.x;
    if (gid >= a.cum[9]) return;
    int j = 0;
    while (gid >= a.cum[j + 1]) j++;
    int idx = gid - a.cum[j];
    int kk = idx & 31;
    int n = (idx >> 5) % a.Nc[j];
    int kt = idx / (32 * a.Nc[j]);
    int k = kt * 32 + kk;
    float v = (k < a.K[j]) ? a.src[j][(size_t)k * a.Nc[j] + n] : 0.f;
    a.dst[j][idx] = __float2bfloat16(v);
}

// ---------------- W_out swizzle: [256][1] -> frag-linear [256x16], col 0 only
__global__ __launch_bounds__(256) void k_swz_wout(const float* __restrict__ Wout,
                                                  __hip_bfloat16* __restrict__ dst)
{
    int idx = blockIdx.x * 256 + threadIdx.x;   // 4096 total
    if (idx >= 8 * 16 * 32) return;
    int kk = idx & 31;
    int n = (idx >> 5) & 15;
    int kt = idx >> 9;
    float v = (n == 0) ? Wout[kt * 32 + kk] : 0.f;
    dst[idx] = __float2bfloat16(v);
}

// ---------------- CSR build
__global__ __launch_bounds__(256) void k_hist(const int* __restrict__ snd,
                                              int* __restrict__ cnt, int E)
{
    int e = blockIdx.x * 256 + threadIdx.x;
    if (e < E) atomicAdd(&cnt[snd[e]], 1);
}

__global__ __launch_bounds__(256) void k_scan(const int* __restrict__ cnt,
                                              int* __restrict__ off,
                                              int* __restrict__ cur, int N)
{
    __shared__ int sums[256];
    int tid = threadIdx.x;
    int chunk = (N + 255) / 256;
    int base = tid * chunk;
    int s = 0;
    for (int i = 0; i < chunk; i++) { int idx = base + i; if (idx < N) s += cnt[idx]; }
    sums[tid] = s;
    __syncthreads();
    for (int d = 1; d < 256; d <<= 1) {
        int v = (tid >= d) ? sums[tid - d] : 0;
        __syncthreads();
        sums[tid] += v;
        __syncthreads();
    }
    int run = (tid == 0) ? 0 : sums[tid - 1];
    for (int i = 0; i < chunk; i++) {
        int idx = base + i;
        if (idx < N) { off[idx] = run; cur[idx] = run; run += cnt[idx]; }
    }
    if (tid == 255) off[N] = run;
}

__global__ __launch_bounds__(256) void k_cscatter(const int* __restrict__ snd,
                                                  int* __restrict__ cur,
                                                  int* __restrict__ eidx, int E)
{
    int e = blockIdx.x * 256 + threadIdx.x;
    if (e >= E) return;
    int p = atomicAdd(&cur[snd[e]], 1);
    eidx[p] = e;
}

// =====================================================================
// Tile kernels (operand-swapped): A-operand = weight frag, B-operand = x frag
// => acc C^T layout: edge = lane&15, outcol = quad*4+reg -> per-thread 4
// consecutive COLUMNS of one edge row: all epilogue writes are packed.
// Block = 64 edges x 4 waves; wave w owns outcol slice 64w..64w+63.
// As holds the GEMM1 input (never overwritten); Ys holds the hidden layer.
// =====================================================================

// ---------------- MFMA embed tile kernel with fused geometry prologue
__global__ __launch_bounds__(256) void k_embed_mfma(
    const float* __restrict__ vec, const float* __restrict__ na,
    const int* __restrict__ snd, const int* __restrict__ rcv,
    const __hip_bfloat16* __restrict__ We0s, const float* __restrict__ be0,
    const __hip_bfloat16* __restrict__ We1s, const float* __restrict__ be1,
    const __hip_bfloat16* __restrict__ Wv0s, const __hip_bfloat16* __restrict__ Wlws0,
    float* __restrict__ ubuf, float* __restrict__ Ybuf,
    __hip_bfloat16* __restrict__ xb, float* __restrict__ abuf,
    float* __restrict__ wbuf)
{
    __shared__ __align__(16) __hip_bfloat16 As[64 * LROW];  // 37888 B
    __shared__ __align__(16) __hip_bfloat16 Ys[64 * YROW];  // 33792 B
    __shared__ float us[64];
    int tid = threadIdx.x;
    int w = tid >> 6, l = tid & 63;
    int lm = l & 15, lq = l >> 4;
    int eb = blockIdx.x * 64;

    // ---- fused geometry: features straight into As; u,Y to global ----
    {
        int el = tid & 63;
        int part = tid >> 6;
        int ge = eb + el;
        if (part == 0) {
            float vx = vec[3 * ge + 0], vy = vec[3 * ge + 1], vz = vec[3 * ge + 2];
            float d = sqrtf(vx * vx + vy * vy + vz * vz);
            float d3 = d * d * d;
            float d6 = d3 * d3, d7 = d6 * d, d8 = d7 * d;
            float u = 1.f - 28.f * d6 + 48.f * d7 - 21.f * d8;
            u = (d < 1.f) ? u : 0.f;
            ubuf[ge] = u;
            us[el] = u;
            float invd = 1.f / d;
            const float SQ2 = 1.41421356237309515f;
            const float PI = 3.14159265358979323846f;
#pragma unroll
            for (int k = 1; k <= NB; k++)
                As[el * LROW + (k - 1)] = __float2bfloat16(SQ2 * sinf((float)k * PI * d) * invd);
#pragma unroll
            for (int j = 40; j < 64; j++) As[el * LROW + j] = __float2bfloat16(0.f);
        } else if (part == 1) {
            int s = snd[ge];
#pragma unroll
            for (int j = 0; j < 16; j++)
                As[el * LROW + 8 + j] = __float2bfloat16(na[(size_t)s * F + j]);
        } else if (part == 2) {
            int r = rcv[ge];
#pragma unroll
            for (int j = 0; j < 16; j++)
                As[el * LROW + 24 + j] = __float2bfloat16(na[(size_t)r * F + j]);
        } else {
            float vx = vec[3 * ge + 0], vy = vec[3 * ge + 1], vz = vec[3 * ge + 2];
            float d = sqrtf(vx * vx + vy * vy + vz * vz);
            float invd = 1.f / d;
            float x = vx * invd, y = vy * invd, z = vz * invd;
            const float s3 = 1.7320508075688772f;
            const float s5 = 2.2360679774997896f;
            const float s15 = 3.8729833462074170f;
            const float s7 = 2.6457513110645907f;
            const float c33 = 2.0916500663351889f;
            const float c32 = 10.246950765959598f;
            const float c31 = 1.6201851746019651f;
            float* Yp = Ybuf + (size_t)ge * 16;
            Yp[0] = 1.f;
            Yp[1] = s3 * x;  Yp[2] = s3 * y;  Yp[3] = s3 * z;
            Yp[4] = s15 * x * y;  Yp[5] = s15 * y * z;
            Yp[6] = 0.5f * s5 * (3.f * z * z - 1.f);
            Yp[7] = s15 * x * z;
            Yp[8] = 0.5f * s15 * (x * x - y * y);
            Yp[9] = c33 * y * (3.f * x * x - y * y);
            Yp[10] = c32 * x * y * z;
            Yp[11] = c31 * y * (5.f * z * z - 1.f);
            Yp[12] = 0.5f * s7 * (5.f * z * z * z - 3.f * z);
            Yp[13] = c31 * x * (5.f * z * z - 1.f);
            Yp[14] = 0.5f * c32 * z * (x * x - y * y);
            Yp[15] = c33 * x * (x * x - 3.f * y * y);
        }
    }
    __syncthreads();

    // GEMM1: [64x64] @ [64x256]  (A=W frag, B=x frag)
    f32x4 acc[4][4];
#pragma unroll
    for (int mt = 0; mt < 4; mt++)
#pragma unroll
        for (int nt = 0; nt < 4; nt++) acc[mt][nt] = (f32x4){0.f, 0.f, 0.f, 0.f};
#pragma unroll
    for (int kt = 0; kt < 2; kt++) {
        bf16x8 aw[4];
#pragma unroll
        for (int nt = 0; nt < 4; nt++)
            aw[nt] = *(const bf16x8*)(We0s + ((size_t)(kt * 256 + w * 64 + nt * 16 + lm) * 32 + lq * 8));
#pragma unroll
        for (int mt = 0; mt < 4; mt++) {
            bf16x8 bx = *(const bf16x8*)(As + (mt * 16 + lm) * LROW + kt * 32 + lq * 8);
#pragma unroll
            for (int nt = 0; nt < 4; nt++) acc[mt][nt] = MFMA_B16(aw[nt], bx, acc[mt][nt]);
        }
    }
    // y0 = silu(acc + b0) -> Ys (disjoint from As: no barrier before writes)
#pragma unroll
    for (int nt = 0; nt < 4; nt++) {
        int cb = w * 64 + nt * 16 + lq * 4;
        f32x4 bb = *(const f32x4*)(be0 + cb);
#pragma unroll
        for (int mt = 0; mt < 4; mt++) {
            int row = mt * 16 + lm;
            bf16x4 v = {f2bs(silu(acc[mt][nt][0] + bb[0])), f2bs(silu(acc[mt][nt][1] + bb[1])),
                        f2bs(silu(acc[mt][nt][2] + bb[2])), f2bs(silu(acc[mt][nt][3] + bb[3]))};
            *(bf16x4*)(Ys + row * YROW + cb) = v;
        }
    }
    __syncthreads();

    // GEMM2: [64x256] @ [256x256]
#pragma unroll
    for (int mt = 0; mt < 4; mt++)
#pragma unroll
        for (int nt = 0; nt < 4; nt++) acc[mt][nt] = (f32x4){0.f, 0.f, 0.f, 0.f};
#pragma unroll
    for (int kt = 0; kt < 8; kt++) {
        bf16x8 aw[4];
#pragma unroll
        for (int nt = 0; nt < 4; nt++)
            aw[nt] = *(const bf16x8*)(We1s + ((size_t)(kt * 256 + w * 64 + nt * 16 + lm) * 32 + lq * 8));
#pragma unroll
        for (int mt = 0; mt < 4; mt++) {
            bf16x8 bx = *(const bf16x8*)(Ys + (mt * 16 + lm) * YROW + kt * 32 + lq * 8);
#pragma unroll
            for (int nt = 0; nt < 4; nt++) acc[mt][nt] = MFMA_B16(aw[nt], bx, acc[mt][nt]);
        }
    }
    // epilogue: x1 = silu(.)*u -> xb global (8B stores) and As (b64)
    // (As features region is dead after GEMM1; writes to cols 0..256 safe
    //  only after all GEMM1 reads -> the Ys sync above already ensured it)
#pragma unroll
    for (int nt = 0; nt < 4; nt++) {
        int cb = w * 64 + nt * 16 + lq * 4;
        f32x4 bb = *(const f32x4*)(be1 + cb);
#pragma unroll
        for (int mt = 0; mt < 4; mt++) {
            int row = mt * 16 + lm;
            float uu = us[row];
            bf16x4 v = {f2bs(silu(acc[mt][nt][0] + bb[0]) * uu),
                        f2bs(silu(acc[mt][nt][1] + bb[1]) * uu),
                        f2bs(silu(acc[mt][nt][2] + bb[2]) * uu),
                        f2bs(silu(acc[mt][nt][3] + bb[3]) * uu)};
            *(bf16x4*)(As + row * LROW + cb) = v;
            *(bf16x4*)(xb + (size_t)(eb + row) * H + cb) = v;
        }
    }
    __syncthreads();

    // GEMM3: a = x@Wv0, w = x@Wlw0 -- wave w owns edges w*16..w*16+15
    f32x4 av = (f32x4){0.f, 0.f, 0.f, 0.f};
    f32x4 aw2 = (f32x4){0.f, 0.f, 0.f, 0.f};
#pragma unroll
    for (int kt = 0; kt < 8; kt++) {
        bf16x8 bx = *(const bf16x8*)(As + (w * 16 + lm) * LROW + kt * 32 + lq * 8);
        bf16x8 a_v = *(const bf16x8*)(Wv0s + ((size_t)(kt * 16 + lm) * 32 + lq * 8));
        bf16x8 a_w = *(const bf16x8*)(Wlws0 + ((size_t)(kt * 16 + lm) * 32 + lq * 8));
        av = MFMA_B16(a_v, bx, av);
        aw2 = MFMA_B16(a_w, bx, aw2);
    }
    *(f32x4*)(abuf + (size_t)(eb + w * 16 + lm) * 16 + lq * 4) = av;
    *(f32x4*)(wbuf + (size_t)(eb + w * 16 + lm) * 16 + lq * 4) = aw2;
}

// ---------------- CSR gather (4 nodes/block): wYn[n,m,i] = inv*sum w[e,m]*Y[e,i]
__global__ __launch_bounds__(256) void k_gather(
    const int* __restrict__ off, const int* __restrict__ eidx,
    const float* __restrict__ wbuf, const float* __restrict__ Ybuf,
    float* __restrict__ wYn)
{
    __shared__ float ws[16][16];
    __shared__ float Ysh[16][16];
    int tid = threadIdx.x;
    int m = tid >> 4, i = tid & 15;
    for (int nn = 0; nn < 4; nn++) {
        int n = blockIdx.x * 4 + nn;
        int beg = off[n], end = off[n + 1];
        float acc = 0.f;
        for (int c = beg; c < end; c += 16) {
            int ne = min(16, end - c);
            int j = tid >> 4, k = tid & 15;
            if (j < ne) {
                int e = eidx[c + j];
                ws[j][k] = wbuf[(size_t)e * 16 + k];
                Ysh[j][k] = Ybuf[(size_t)e * 16 + k];
            }
            __syncthreads();
            for (int j2 = 0; j2 < ne; j2++) acc += ws[j2][m] * Ysh[j2][i];
            __syncthreads();
        }
        wYn[(size_t)n * 256 + m * 16 + i] = acc * 0.25f;
    }
}

// ---------------- MFMA layer tile kernel (operand-swapped, dual buffer)
__global__ __launch_bounds__(256) void k_layer_mfma(
    __hip_bfloat16* __restrict__ xb, const float* __restrict__ abuf,
    const float* __restrict__ Ybuf, const float* __restrict__ ubuf,
    const int* __restrict__ snd, const int* __restrict__ rcv,
    const float* __restrict__ wYn0, const float* __restrict__ wYn1,
    const float* __restrict__ Wlsh,
    const __hip_bfloat16* __restrict__ W1s, const float* __restrict__ b1,
    const __hip_bfloat16* __restrict__ W2s, const float* __restrict__ b2,
    const __hip_bfloat16* __restrict__ Wlwn, float* __restrict__ wbufn,
    const __hip_bfloat16* __restrict__ Wouts, float* __restrict__ nacc,
    int layer)
{
    __shared__ __align__(16) __hip_bfloat16 As[64 * LROW];  // x | vv | 0
    __shared__ __align__(16) __hip_bfloat16 Ys[64 * YROW];  // hidden
    int tid = threadIdx.x;
    int w = tid >> 6, l = tid & 63;
    int lm = l & 15, lq = l >> 4;
    int eb = blockIdx.x * 64;

    // stage x tile [64x256] -> As cols 0..256
#pragma unroll
    for (int i = 0; i < 8; i++) {
        int c = tid + 256 * i;
        int row = c >> 5, kc = c & 31;
        *(bf16x8*)(As + row * LROW + kc * 8) =
            *(const bf16x8*)(xb + (size_t)(eb + row) * H + kc * 8);
    }
    // vv prologue -> As cols 256..272; zeros 272..288
    {
        int el = tid & 63;
        int mh = (tid >> 6) * 4;
        int ge = eb + el;
        int s = snd[ge];
        const float* w0 = wYn0 + (size_t)s * 256;
        float Yr[16];
        if (layer == 1) {
#pragma unroll
            for (int i = 0; i < 16; i++)
                Yr[i] = Ybuf[(size_t)ge * 16 + i] * Wlsh[i * 16];
        }
#pragma unroll
        for (int mi = 0; mi < 4; mi++) {
            int m = mh + mi;
            float a = abuf[(size_t)ge * 16 + m];
            float vv;
            if (layer == 0) {
                vv = w0[m * 16] * a;  // Y[e][0] == 1
            } else {
                float t = 0.f;
#pragma unroll
                for (int i = 0; i < 16; i++) t += w0[m * 16 + i] * Yr[i];
                vv = wYn1[(size_t)s * 256 + m * 16] * a * t;
            }
            As[el * LROW + 256 + m] = __float2bfloat16(vv);
        }
        if (tid < 64) {
#pragma unroll
            for (int j = 0; j < 16; j++) As[tid * LROW + 272 + j] = __float2bfloat16(0.f);
        }
    }
    __syncthreads();

    float uu[4];
#pragma unroll
    for (int mt = 0; mt < 4; mt++) uu[mt] = ubuf[eb + mt * 16 + lm];

    // GEMM1: [64x288] @ [288x256]
    f32x4 acc[4][4];
#pragma unroll
    for (int mt = 0; mt < 4; mt++)
#pragma unroll
        for (int nt = 0; nt < 4; nt++) acc[mt][nt] = (f32x4){0.f, 0.f, 0.f, 0.f};
#pragma unroll
    for (int kt = 0; kt < 9; kt++) {
        bf16x8 aw[4];
#pragma unroll
        for (int nt = 0; nt < 4; nt++)
            aw[nt] = *(const bf16x8*)(W1s + ((size_t)(kt * 256 + w * 64 + nt * 16 + lm) * 32 + lq * 8));
#pragma unroll
        for (int mt = 0; mt < 4; mt++) {
            bf16x8 bx = *(const bf16x8*)(As + (mt * 16 + lm) * LROW + kt * 32 + lq * 8);
#pragma unroll
            for (int nt = 0; nt < 4; nt++) acc[mt][nt] = MFMA_B16(aw[nt], bx, acc[mt][nt]);
        }
    }
    // y1 = silu(acc + b1) -> Ys packed (disjoint from As)
#pragma unroll
    for (int nt = 0; nt < 4; nt++) {
        int cb = w * 64 + nt * 16 + lq * 4;
        f32x4 bb = *(const f32x4*)(b1 + cb);
#pragma unroll
        for (int mt = 0; mt < 4; mt++) {
            int row = mt * 16 + lm;
            bf16x4 v = {f2bs(silu(acc[mt][nt][0] + bb[0])), f2bs(silu(acc[mt][nt][1] + bb[1])),
                        f2bs(silu(acc[mt][nt][2] + bb[2])), f2bs(silu(acc[mt][nt][3] + bb[3]))};
            *(bf16x4*)(Ys + row * YROW + cb) = v;
        }
    }
    __syncthreads();

    // GEMM2: [64x256] @ [256x256]
#pragma unroll
    for (int mt = 0; mt < 4; mt++)
#pragma unroll
        for (int nt = 0; nt < 4; nt++) acc[mt][nt] = (f32x4){0.f, 0.f, 0.f, 0.f};
#pragma unroll
    for (int kt = 0; kt < 8; kt++) {
        bf16x8 aw[4];
#pragma unroll
        for (int nt = 0; nt < 4; nt++)
            aw[nt] = *(const bf16x8*)(W2s + ((size_t)(kt * 256 + w * 64 + nt * 16 + lm) * 32 + lq * 8));
#pragma unroll
        for (int mt = 0; mt < 4; mt++) {
            bf16x8 bx = *(const bf16x8*)(Ys + (mt * 16 + lm) * YROW + kt * 32 + lq * 8);
#pragma unroll
            for (int nt = 0; nt < 4; nt++) acc[mt][nt] = MFMA_B16(aw[nt], bx, acc[mt][nt]);
        }
    }
    // epilogue: xnew = (x_old + u*silu(acc+b2))/sqrt2; x_old read b64 from As;
    // same thread writes same cells (WAR-safe, no barrier).
    const float rs2 = 0.70710678118654752f;
#pragma unroll
    for (int nt = 0; nt < 4; nt++) {
        int cb = w * 64 + nt * 16 + lq * 4;
        f32x4 bb = *(const f32x4*)(b2 + cb);
#pragma unroll
        for (int mt = 0; mt < 4; mt++) {
            int row = mt * 16 + lm;
            bf16x4 xo = *(const bf16x4*)(As + row * LROW + cb);
            bf16x4 v;
#pragma unroll
            for (int r = 0; r < 4; r++) {
                float xn = (bs2f(xo[r]) + uu[mt] * silu(acc[mt][nt][r] + bb[r])) * rs2;
                v[r] = f2bs(xn);
            }
            *(bf16x4*)(As + row * LROW + cb) = v;
            if (layer == 0) *(bf16x4*)(xb + (size_t)(eb + row) * H + cb) = v;
        }
    }
    __syncthreads();

    if (layer == 0) {
        // wcomp: w = x_new @ Wlwn -- wave w owns edges w*16..w*16+15
        f32x4 cw = (f32x4){0.f, 0.f, 0.f, 0.f};
#pragma unroll
        for (int kt = 0; kt < 8; kt++) {
            bf16x8 bx = *(const bf16x8*)(As + (w * 16 + lm) * LROW + kt * 32 + lq * 8);
            bf16x8 a = *(const bf16x8*)(Wlwn + ((size_t)(kt * 16 + lm) * 32 + lq * 8));
            cw = MFMA_B16(a, bx, cw);
        }
        *(f32x4*)(wbufn + (size_t)(eb + w * 16 + lm) * 16 + lq * 4) = cw;
    } else {
        // out-proj: edge_out = (x_new @ W_out) * u -> atomicAdd nacc[rcv]
        f32x4 co = (f32x4){0.f, 0.f, 0.f, 0.f};
#pragma unroll
        for (int kt = 0; kt < 8; kt++) {
            bf16x8 bx = *(const bf16x8*)(As + (w * 16 + lm) * LROW + kt * 32 + lq * 8);
            bf16x8 a = *(const bf16x8*)(Wouts + ((size_t)(kt * 16 + lm) * 32 + lq * 8));
            co = MFMA_B16(a, bx, co);
        }
        if (lq == 0) {
            int e = eb + w * 16 + lm;
            atomicAdd(&nacc[rcv[e]], co[0] * ubuf[e]);
        }
    }
}

__global__ __launch_bounds__(256) void k_final(
    const float* __restrict__ nacc, void* __restrict__ out, const int* __restrict__ flag,
    float inv, int N)
{
    int n = blockIdx.x * 256 + threadIdx.x;
    if (n >= N) return;
    float v = nacc[n] * inv;
    if (*flag) ((float*)out)[n] = v;
    else       ((__hip_bfloat16*)out)[n] = __float2bfloat16(v);
}

extern "C" void kernel_launch(void* const* d_in, const int* in_sizes, int n_in,
                              void* d_out, int out_size, void* d_ws, size_t ws_size,
                              hipStream_t stream)
{
    const int E = in_sizes[2];      // 131072
    const int N = in_sizes[0] / F;  // 8192
    (void)n_in; (void)ws_size; (void)out_size;

    char* wsb = (char*)d_ws;
    size_t off = 0;
    int* flag = (int*)wsb; off += 256;

    const int fidx[14] = {0, 1, 4, 5, 6, 7, 8, 9, 10, 11, 12, 13, 14, 15};
    float* canon[14];
    for (int k = 0; k < 14; k++) {
        canon[k] = (float*)(wsb + off);
        off += (size_t)in_sizes[fidx[k]] * 4;
        off = (off + 255) & ~(size_t)255;
    }
    const float* naC   = canon[0];
    const float* vecC  = canon[1];
    const float* We0C  = canon[2];
    const float* be0C  = canon[3];
    const float* We1C  = canon[4];
    const float* be1C  = canon[5];
    const float* Wv0C  = canon[6];
    const float* WlwC  = canon[7];
    const float* WlshC = canon[8];
    const float* Wly1C = canon[9];
    const float* bly1C = canon[10];
    const float* Wly2C = canon[11];
    const float* bly2C = canon[12];
    const float* WoutC = canon[13];

    // swizzled bf16 weights
    __hip_bfloat16* We0s  = (__hip_bfloat16*)(wsb + off); off += 64 * 256 * 2;
    __hip_bfloat16* We1s  = (__hip_bfloat16*)(wsb + off); off += 256 * 256 * 2;
    __hip_bfloat16* Wv0s  = (__hip_bfloat16*)(wsb + off); off += 256 * 16 * 2;
    __hip_bfloat16* Wlws0 = (__hip_bfloat16*)(wsb + off); off += 256 * 16 * 2;
    __hip_bfloat16* Wlws1 = (__hip_bfloat16*)(wsb + off); off += 256 * 16 * 2;
    __hip_bfloat16* W1s0  = (__hip_bfloat16*)(wsb + off); off += 288 * 256 * 2;
    __hip_bfloat16* W1s1  = (__hip_bfloat16*)(wsb + off); off += 288 * 256 * 2;
    __hip_bfloat16* W2s0  = (__hip_bfloat16*)(wsb + off); off += 256 * 256 * 2;
    __hip_bfloat16* W2s1  = (__hip_bfloat16*)(wsb + off); off += 256 * 256 * 2;
    __hip_bfloat16* Wouts = (__hip_bfloat16*)(wsb + off); off += 256 * 16 * 2;
    off = (off + 255) & ~(size_t)255;

    __hip_bfloat16* xbuf = (__hip_bfloat16*)(wsb + off); off += (size_t)E * H * 2;
    float* wYn0 = (float*)(wsb + off); off += (size_t)N * H * 4;
    float* wYn1 = (float*)(wsb + off); off += (size_t)N * H * 4;
    float* ubuf = (float*)(wsb + off); off += (size_t)E * 4;
    float* Ybuf = (float*)(wsb + off); off += (size_t)E * 16 * 4;
    float* abuf = (float*)(wsb + off); off += (size_t)E * 16 * 4;
    float* wbuf = (float*)(wsb + off); off += (size_t)E * 16 * 4;
    float* nacc = (float*)(wsb + off); off += (size_t)N * 4;
    int* cnt  = (int*)(wsb + off); off += (size_t)N * 4;
    int* offb = (int*)(wsb + off); off += (size_t)(N + 1) * 4;
    int* cur  = (int*)(wsb + off); off += (size_t)N * 4;
    int* eidx = (int*)(wsb + off); off += (size_t)E * 4;

    const int* snd = (const int*)d_in[2];
    const int* rcv = (const int*)d_in[3];
    const float inv = 0.25f;
    const int nb64 = E / 64;

    // dtype sniff + merged canonicalization
    k_sniff<<<1, 256, 0, stream>>>(d_in[1], flag);
    {
        ConvArgs ca;
        int c = 0;
        for (int k = 0; k < 14; k++) {
            ca.src[k] = d_in[fidx[k]];
            ca.dst[k] = canon[k];
            ca.cum[k] = c;
            c += in_sizes[fidx[k]];
        }
        ca.cum[14] = c;
        k_conv_all<<<(c + 255) / 256, 256, 0, stream>>>(ca, flag);
    }

    // merged weight swizzles
    {
        SwzArgs sa;
        const float* srcs[9] = {We0C, We1C, Wv0C, WlwC, WlwC + 256 * 16,
                                Wly1C, Wly1C + 272 * 256, Wly2C, Wly2C + 256 * 256};
        __hip_bfloat16* dsts[9] = {We0s, We1s, Wv0s, Wlws0, Wlws1, W1s0, W1s1, W2s0, W2s1};
        int Ks[9]    = {40, 256, 256, 256, 256, 272, 272, 256, 256};
        int Ncs[9]   = {256, 256, 16, 16, 16, 256, 256, 256, 256};
        int Kpads[9] = {64, 256, 256, 256, 256, 288, 288, 256, 256};
        int c = 0;
        for (int j = 0; j < 9; j++) {
            sa.src[j] = srcs[j]; sa.dst[j] = dsts[j];
            sa.K[j] = Ks[j]; sa.Nc[j] = Ncs[j];
            sa.cum[j] = c;
            c += (Kpads[j] >> 5) * Ncs[j] * 32;
        }
        sa.cum[9] = c;
        k_swz_all<<<(c + 255) / 256, 256, 0, stream>>>(sa);
    }
    k_swz_wout<<<16, 256, 0, stream>>>(WoutC, Wouts);

    // sender CSR
    hipMemsetAsync(cnt, 0, (size_t)N * sizeof(int), stream);
    k_hist<<<(E + 255) / 256, 256, 0, stream>>>(snd, cnt, E);
    k_scan<<<1, 256, 0, stream>>>(cnt, offb, cur, N);
    k_cscatter<<<(E + 255) / 256, 256, 0, stream>>>(snd, cur, eidx, E);

    // embed (fused geometry)
    k_embed_mfma<<<nb64, 256, 0, stream>>>(vecC, naC, snd, rcv,
                                           We0s, be0C, We1s, be1C, Wv0s, Wlws0,
                                           ubuf, Ybuf, xbuf, abuf, wbuf);

    // layer 0 (emits w for layer 1 into wbuf)
    k_gather<<<N / 4, 256, 0, stream>>>(offb, eidx, wbuf, Ybuf, wYn0);
    k_layer_mfma<<<nb64, 256, 0, stream>>>(xbuf, abuf, Ybuf, ubuf, snd, rcv, wYn0, wYn0,
                                           WlshC, W1s0, bly1C, W2s0, bly2C,
                                           Wlws1, wbuf, (const __hip_bfloat16*)nullptr,
                                           (float*)nullptr, 0);
    // layer 1 (residual in LDS; fused output projection -> nacc)
    hipMemsetAsync(nacc, 0, (size_t)N * sizeof(float), stream);
    k_gather<<<N / 4, 256, 0, stream>>>(offb, eidx, wbuf, Ybuf, wYn1);
    k_layer_mfma<<<nb64, 256, 0, stream>>>(xbuf, abuf, Ybuf, ubuf, snd, rcv, wYn0, wYn1,
                                           WlshC, W1s1, bly1C + H, W2s1, bly2C + H,
                                           (const __hip_bfloat16*)nullptr, (float*)nullptr,
                                           Wouts, nacc, 1);

    k_final<<<(N + 255) / 256, 256, 0, stream>>>(nacc, d_out, flag, inv, N);
}